// Round 6
// baseline (159.043 us; speedup 1.0000x reference)
//
#include <hip/hip_runtime.h>
#include <stdint.h>

#define NB 8
#define NN 107136
#define TOTAL (NB * NN)
#define NPAIR (NN / 2)       // 53568
#define PRE 2048
#define POST 128
#define CAP 4096
#define HBINS 128            // 16-bit key bins restricted to s in [0.5, 1)
#define KEYBASE 0xBF00u
#define SCORE_TH 0.05f
#define SH_BPB 14            // score blocks per batch (14*4096 >= 53568 pairs)

// ---------------- ws layout (bytes) ----------------
static constexpr size_t OFF_SCORES = 0;
static constexpr size_t SZ_SCORES  = (size_t)TOTAL * 4;
static constexpr size_t OFF_HIST   = OFF_SCORES + SZ_SCORES;       // partial hists, 14 segs
static constexpr size_t SZ_HIST    = (size_t)NB * SH_BPB * HBINS * 4;
static constexpr size_t OFF_CNT    = OFF_HIST + SZ_HIST;           // 8 x 64 u32 (256B apart)
static constexpr size_t SZ_CNT     = (size_t)NB * 64 * 4;
static constexpr size_t OFF_CAND   = OFF_CNT + SZ_CNT + 256;
static constexpr size_t SZ_CAND    = (size_t)NB * CAP * 8;
static constexpr size_t OFF_RANK   = OFF_CAND + SZ_CAND;           // rank accumulators
static constexpr size_t SZ_RANK    = (size_t)NB * CAP * 4;

// ---------------- kernels ----------------

// fused softmax scores + per-segment partial 128-bin histogram (unconditional write,
// no pre-zero needed) + zero counts/cand/rankArr
__global__ void __launch_bounds__(256) k_scoreshist(const float* __restrict__ cls,
                                                    float* __restrict__ scores,
                                                    uint32_t* __restrict__ hp,
                                                    uint32_t* __restrict__ counts,
                                                    uint64_t* __restrict__ cand,
                                                    uint32_t* __restrict__ rankArr) {
    int b = blockIdx.y;
    int t = threadIdx.x;
    if (blockIdx.x == 0 && t == 0) counts[(size_t)b * 64] = 0u;
    for (int i = blockIdx.x * 256 + t; i < CAP; i += SH_BPB * 256) {
        cand[(size_t)b * CAP + i] = 0ull;          // rank padding: zeros are rank-neutral
        rankArr[(size_t)b * CAP + i] = 0u;
    }
    __shared__ uint32_t lh[HBINS];
    if (t < HBINS) lh[t] = 0u;
    __syncthreads();
    const float4* cp = (const float4*)cls + (size_t)b * NPAIR;
    float2* sp = (float2*)scores + (size_t)b * NPAIR;
#pragma unroll
    for (int k = 0; k < 16; k++) {
        int p = blockIdx.x * 4096 + k * 256 + t;
        if (p < NPAIR) {
            float4 c = cp[p];
            float m0 = fmaxf(c.x, c.y);
            float s0 = __fdiv_rn(expf(__fsub_rn(c.y, m0)),
                                 __fadd_rn(expf(__fsub_rn(c.x, m0)), expf(__fsub_rn(c.y, m0))));
            float m1 = fmaxf(c.z, c.w);
            float s1 = __fdiv_rn(expf(__fsub_rn(c.w, m1)),
                                 __fadd_rn(expf(__fsub_rn(c.z, m1)), expf(__fsub_rn(c.w, m1))));
            sp[p] = make_float2(s0, s1);
            if (s0 >= 0.5f) {
                uint32_t bin = ((__float_as_uint(s0) >> 16) | 0x8000u) - KEYBASE;
                if (bin > 127u) bin = 127u;
                atomicAdd(&lh[bin], 1u);
            }
            if (s1 >= 0.5f) {
                uint32_t bin = ((__float_as_uint(s1) >> 16) | 0x8000u) - KEYBASE;
                if (bin > 127u) bin = 127u;
                atomicAdd(&lh[bin], 1u);
            }
        }
    }
    __syncthreads();
    if (t < HBINS) hp[((size_t)b * SH_BPB + blockIdx.x) * HBINS + t] = lh[t];
}

// compact with inline per-wave threshold-find (sums 14 partial hists: 28 loads/lane)
__global__ void __launch_bounds__(256) k_compact(const float* __restrict__ scores,
                                                 const uint32_t* __restrict__ hp,
                                                 uint32_t* __restrict__ counts,
                                                 uint64_t* __restrict__ cand) {
    int g2 = blockIdx.x * 256 + threadIdx.x;      // pair index; grid exact
    int lane = threadIdx.x & 63, wid = threadIdx.x >> 6;
    int e0 = 2 * g2;
    int b = e0 / NN;                              // wave-uniform (NN % 128 == 0)

    // ---- wave-redundant findT over 14-segment partial hists ----
    const uint32_t* hb = hp + (size_t)b * SH_BPB * HBINS;
    uint32_t h0 = 0, h1 = 0;
#pragma unroll
    for (int sg = 0; sg < SH_BPB; sg++) {
        h0 += hb[sg * HBINS + 2 * lane];
        h1 += hb[sg * HBINS + 2 * lane + 1];
    }
    uint32_t v = h0 + h1;
    for (int off = 1; off < 64; off <<= 1) {
        uint32_t u = __shfl_down(v, off);
        if (lane + off >= 64) u = 0u;
        v += u;
    }
    uint32_t total = __shfl(v, 0);
    int c = -1;
    if (v - h0 >= PRE) c = 2 * lane + 1;
    else if (v >= PRE) c = 2 * lane;
    for (int off = 32; off > 0; off >>= 1) c = max(c, __shfl_xor(c, off));
    uint32_t Tb = (total >= PRE && c >= 0) ? (KEYBASE + (uint32_t)c) : 0u;

    // ---- threshold test + block-aggregated slot reservation ----
    float2 sv = ((const float2*)scores)[g2];
    uint32_t key0 = __float_as_uint(sv.x) | 0x80000000u;
    uint32_t key1 = __float_as_uint(sv.y) | 0x80000000u;
    bool p0 = (sv.x >= SCORE_TH) && ((key0 >> 16) >= Tb);
    bool p1 = (sv.y >= SCORE_TH) && ((key1 >> 16) >= Tb);
    uint64_t bal0 = __ballot(p0), bal1 = __ballot(p1);
    uint32_t n0 = (uint32_t)__popcll(bal0);
    uint32_t wcnt = n0 + (uint32_t)__popcll(bal1);
    uint64_t below = (1ull << lane) - 1ull;
    uint32_t off0 = (uint32_t)__popcll(bal0 & below);
    uint32_t off1 = n0 + (uint32_t)__popcll(bal1 & below);
    __shared__ uint32_t lcnt[2];
    __shared__ uint32_t gbase[2];
    __shared__ uint32_t wbase[4];
    int b0 = (blockIdx.x * 512) / NN;
    if (threadIdx.x < 2) lcnt[threadIdx.x] = 0u;
    __syncthreads();
    if (lane == 0 && wcnt) wbase[wid] = atomicAdd(&lcnt[b - b0], wcnt);
    __syncthreads();
    if (threadIdx.x < 2 && lcnt[threadIdx.x])
        gbase[threadIdx.x] = atomicAdd(&counts[(size_t)(b0 + threadIdx.x) * 64], lcnt[threadIdx.x]);
    __syncthreads();
    if (p0 | p1) {
        uint32_t base = gbase[b - b0] + wbase[wid];
        if (p0) {
            uint32_t slot = base + off0;
            if (slot < CAP)
                cand[(size_t)b * CAP + slot] =
                    ((uint64_t)key0 << 32) | (uint64_t)(0xFFFFFFFFu - (uint32_t)(e0 - b * NN));
        }
        if (p1) {
            uint32_t slot = base + off1;
            if (slot < CAP)
                cand[(size_t)b * CAP + slot] =
                    ((uint64_t)key1 << 32) | (uint64_t)(0xFFFFFFFFu - (uint32_t)(e0 + 1 - b * NN));
        }
    }
}

// partial rank: block (ib, jt, b) ranks 256 candidates against one 512-key j-tile.
__global__ void __launch_bounds__(256) k_rank_part(const uint64_t* __restrict__ cand,
                                                   const uint32_t* __restrict__ counts,
                                                   uint32_t* __restrict__ rankArr) {
    int b = blockIdx.z;
    int m = (int)counts[(size_t)b * 64]; if (m > CAP) m = CAP;
    int i0 = blockIdx.x * 256;
    int jb = blockIdx.y * 512;
    if (i0 >= m || jb >= m) return;               // block-uniform exit
    int t = threadIdx.x;
    const uint64_t* cb = cand + (size_t)b * CAP;
    uint64_t mykey = cb[i0 + t];                  // padded region is zeros: rank-neutral
    __shared__ uint64_t tile[512];
    tile[t] = cb[jb + t];
    tile[t + 256] = cb[jb + 256 + t];
    __syncthreads();
    if (i0 + t >= m) return;                      // no barriers after this point
    uint32_t rank = 0;
#pragma unroll 16
    for (int j = 0; j < 512; j++)
        rank += (tile[j] > mykey) ? 1u : 0u;
    if (rank) atomicAdd(&rankArr[(size_t)b * CAP + i0 + t], rank);
}

// fused: gather ranked candidates -> decode bbox/area into LDS -> greedy NMS scan
// -> finalize (re-decode only the <=128 kept boxes). One block per batch.
__global__ void __launch_bounds__(512) k_nms_fused(
        const uint64_t* __restrict__ cand, const uint32_t* __restrict__ counts,
        const uint32_t* __restrict__ rankArr,
        const float* __restrict__ box_preds, const float* __restrict__ anchors,
        const float* __restrict__ dir_preds, float* __restrict__ out) {
    int b = blockIdx.x;
    int t = threadIdx.x;
    __shared__ float4 sbb[PRE];        // 32 KiB
    __shared__ float  sar[PRE];        // 8 KiB
    __shared__ uint64_t sKey[PRE];     // 16 KiB
    __shared__ int keptIdx[POST];
    __shared__ int keptCountSh;
    int m = (int)counts[(size_t)b * 64]; if (m > CAP) m = CAP;
    int Mv = (m > PRE) ? PRE : m;
    const uint64_t* cb = cand + (size_t)b * CAP;

    // stage: decode every candidate with rank < PRE directly into its sorted slot
    for (int i = t; i < m; i += 512) {
        uint32_t r = rankArr[(size_t)b * CAP + i];
        if (r >= PRE) continue;
        uint64_t key = cb[i];
        uint32_t idx = 0xFFFFFFFFu - (uint32_t)(key & 0xFFFFFFFFull);
        const float* bp = box_preds + ((size_t)b * NN + idx) * 7;
        const float* an = anchors + ((size_t)b * NN + idx) * 7;
        float xa = an[0], ya = an[1], wa = an[3], la = an[4], ra = an[6];
        float xt = bp[0], yt = bp[1], wt = bp[3], lt = bp[4], rt = bp[6];
        float diag = sqrtf(__fadd_rn(__fmul_rn(la, la), __fmul_rn(wa, wa)));
        float xg = __fadd_rn(__fmul_rn(xt, diag), xa);
        float yg = __fadd_rn(__fmul_rn(yt, diag), ya);
        float lg = __fmul_rn(expf(lt), la);
        float wg = __fmul_rn(expf(wt), wa);
        float rg = __fadd_rn(rt, ra);
        float cc = fabsf(cosf(rg)), ss = fabsf(sinf(rg));
        float hx = __fmul_rn(0.5f, __fadd_rn(__fmul_rn(wg, cc), __fmul_rn(lg, ss)));
        float hy = __fmul_rn(0.5f, __fadd_rn(__fmul_rn(wg, ss), __fmul_rn(lg, cc)));
        float x1 = __fsub_rn(xg, hx), y1 = __fsub_rn(yg, hy);
        float x2 = __fadd_rn(xg, hx), y2 = __fadd_rn(yg, hy);
        sbb[r] = make_float4(x1, y1, x2, y2);
        sar[r] = __fmul_rn(__fsub_rn(x2, x1), __fsub_rn(y2, y1));
        sKey[r] = key;
    }
    __syncthreads();

    // greedy NMS scan: wave 0 only, kept list in lane registers
    if (t < 64) {
        int lane = t;
        float ax1 = 1e30f, ay1 = 1e30f, ax2 = 1e30f, ay2 = 1e30f, aar = 0.f;
        float bx1 = 1e30f, by1 = 1e30f, bx2 = 1e30f, by2 = 1e30f, bar = 0.f;
        int kc = 0;
        for (int i = 0; i < Mv && kc < POST; i++) {
            float4 c = sbb[i];             // broadcast ds_read_b128
            float ca = sar[i];
            float ix = fmaxf(0.f, __fsub_rn(fminf(ax2, c.z), fmaxf(ax1, c.x)));
            float iy = fmaxf(0.f, __fsub_rn(fminf(ay2, c.w), fmaxf(ay1, c.y)));
            float inter = __fmul_rn(ix, iy);
            float den = fmaxf(__fsub_rn(__fadd_rn(aar, ca), inter), 1e-8f);
            bool sup = inter > __fmul_rn(0.5f, den);
            ix = fmaxf(0.f, __fsub_rn(fminf(bx2, c.z), fmaxf(bx1, c.x)));
            iy = fmaxf(0.f, __fsub_rn(fminf(by2, c.w), fmaxf(by1, c.y)));
            inter = __fmul_rn(ix, iy);
            den = fmaxf(__fsub_rn(__fadd_rn(bar, ca), inter), 1e-8f);
            sup = sup || (inter > __fmul_rn(0.5f, den));
            if (__ballot(sup) == 0ull) {
                if (lane == 0) keptIdx[kc] = i;
                if (kc < 64) {
                    if (lane == kc) { ax1 = c.x; ay1 = c.y; ax2 = c.z; ay2 = c.w; aar = ca; }
                } else {
                    if (lane == kc - 64) { bx1 = c.x; by1 = c.y; bx2 = c.z; by2 = c.w; bar = ca; }
                }
                kc++;
            }
        }
        if (lane == 0) keptCountSh = kc;
    }
    __syncthreads();

    // finalize: re-decode the kept boxes (bit-identical op sequence) and emit
    int kc = keptCountSh;
    if (t < POST) {
        size_t ob = (size_t)b * POST + t;
        float box[7] = {0.f, 0.f, 0.f, 0.f, 0.f, 0.f, 0.f};
        float sc = 0.f, mk = 0.f;
        if (t < kc) {
            uint64_t key = sKey[keptIdx[t]];
            float s = __uint_as_float((uint32_t)(key >> 32) & 0x7FFFFFFFu);
            uint32_t idx = 0xFFFFFFFFu - (uint32_t)(key & 0xFFFFFFFFull);
            const float* bp = box_preds + ((size_t)b * NN + idx) * 7;
            const float* an = anchors + ((size_t)b * NN + idx) * 7;
            float xa = an[0], ya = an[1], za = an[2], wa = an[3], la = an[4], ha = an[5], ra = an[6];
            float xt = bp[0], yt = bp[1], zt = bp[2], wt = bp[3], lt = bp[4], ht = bp[5], rt = bp[6];
            float za2  = __fadd_rn(za, __fmul_rn(ha, 0.5f));
            float diag = sqrtf(__fadd_rn(__fmul_rn(la, la), __fmul_rn(wa, wa)));
            float xg = __fadd_rn(__fmul_rn(xt, diag), xa);
            float yg = __fadd_rn(__fmul_rn(yt, diag), ya);
            float zg = __fadd_rn(__fmul_rn(zt, ha), za2);
            float lg = __fmul_rn(expf(lt), la);
            float wg = __fmul_rn(expf(wt), wa);
            float hg = __fmul_rn(expf(ht), ha);
            float rg = __fadd_rn(rt, ra);
            zg = __fsub_rn(zg, __fmul_rn(hg, 0.5f));
            float d0 = dir_preds[((size_t)b * NN + idx) * 2 + 0];
            float d1 = dir_preds[((size_t)b * NN + idx) * 2 + 1];
            float label = (d1 > d0) ? 1.0f : 0.0f;
            const float period = 3.14159265358979323846f;
            float dir_rot = __fsub_rn(rg, __fmul_rn(floorf(__fdiv_rn(rg, period)), period));
            float nr = __fadd_rn(dir_rot, __fmul_rn(period, label));
            bool in_range = (xg >= 0.0f) && (yg >= -39.68f) && (zg >= -5.0f) &&
                            (xg <= 69.12f) && (yg <= 39.68f) && (zg <= 5.0f);
            if (in_range) {
                box[0] = xg; box[1] = yg; box[2] = zg;
                box[3] = wg; box[4] = lg; box[5] = hg; box[6] = nr;
                sc = s; mk = 1.f;
            }
        }
        float* out_b = out;
        float* out_s = out + 7168;
        float* out_l = out + 8192;
        float* out_m = out + 9216;
        for (int c = 0; c < 7; c++) out_b[ob * 7 + c] = box[c];
        out_s[ob] = sc;
        out_l[ob] = 0.f;
        out_m[ob] = mk;
    }
}

extern "C" void kernel_launch(void* const* d_in, const int* in_sizes, int n_in,
                              void* d_out, int out_size, void* d_ws, size_t ws_size,
                              hipStream_t stream) {
    const float* box_preds = (const float*)d_in[0];
    const float* cls_preds = (const float*)d_in[1];
    const float* dir_preds = (const float*)d_in[2];
    const float* anchors   = (const float*)d_in[3];
    float* out = (float*)d_out;
    char* ws = (char*)d_ws;

    float*    scores = (float*)(ws + OFF_SCORES);
    uint32_t* hp     = (uint32_t*)(ws + OFF_HIST);
    uint32_t* counts = (uint32_t*)(ws + OFF_CNT);
    uint64_t* cand   = (uint64_t*)(ws + OFF_CAND);
    uint32_t* rankA  = (uint32_t*)(ws + OFF_RANK);

    dim3 gSH(SH_BPB, NB);
    k_scoreshist<<<gSH, 256, 0, stream>>>(cls_preds, scores, hp, counts, cand, rankA);
    k_compact<<<TOTAL / 512, 256, 0, stream>>>(scores, hp, counts, cand);
    dim3 gRank(CAP / 256, CAP / 512, NB);
    k_rank_part<<<gRank, 256, 0, stream>>>(cand, counts, rankA);
    k_nms_fused<<<NB, 512, 0, stream>>>(cand, counts, rankA, box_preds, anchors,
                                        dir_preds, out);
}